// Round 9
// baseline (876.964 us; speedup 1.0000x reference)
//
#include <hip/hip_runtime.h>
#include <math.h>

#define S_LEN 1024
#define N_HEAD 8
#define P_LEN 2047
#define B_SZ 8
#define QT 32
#define KT 32

typedef __attribute__((ext_vector_type(8))) short bf16x8;
typedef __attribute__((ext_vector_type(4))) float f32x4;

union f4u { float4 v; float f[4]; };
union bfz { bf16x8 v; uint4 u; };

__device__ __forceinline__ unsigned short f2bf(float x) {
  unsigned b = __float_as_uint(x);
  b = b + 0x7FFF + ((b >> 16) & 1);
  return (unsigned short)(b >> 16);
}
__device__ __forceinline__ float bf2f(unsigned short h) {
  return __uint_as_float(((unsigned)h) << 16);
}

// ---------------- mask normalize ------------------------------------------
__global__ __launch_bounds__(256) void mask_prep(const void* __restrict__ mask,
                                                 int* __restrict__ mw) {
  const unsigned int* u = (const unsigned int*)mask;
  bool all01 = true, allf = true;
#pragma unroll
  for (int j = 0; j < 16; ++j) {
    unsigned int x = u[j];
    all01 &= (x <= 1u);
    allf &= (x == 0u || x == 0x3f800000u);
  }
  int i = blockIdx.x * 256 + threadIdx.x;
  int v;
  if (all01) v = (((const int*)mask)[i] != 0);
  else if (allf) v = (((const float*)mask)[i] != 0.0f);
  else v = (((const unsigned char*)mask)[i] != 0);
  mw[i] = v;
}

// ---------------- C = A(MxK) @ W(NxK)^T + bias, K=N=512 -------------------
template<int MODE>
__global__ __launch_bounds__(256) void gemm512(
    const float* __restrict__ A, const float* __restrict__ W,
    const float* __restrict__ bias, const float* __restrict__ pbu,
    const float* __restrict__ pbv, float* __restrict__ fo,
    unsigned short* __restrict__ o1h, unsigned short* __restrict__ o1l,
    unsigned short* __restrict__ o2h, unsigned short* __restrict__ o2l,
    int M)
{
  __shared__ float As[64][36];
  __shared__ float Wt[32][68];
  const int tid = threadIdx.x;
  const int ty = tid >> 4, tx = tid & 15;
  const int m0 = blockIdx.x * 64, n0 = blockIdx.y * 64;
  const int lr = tid >> 3;
  const int lc = (tid & 7) << 2;
  float acc[4][4] = {};

  for (int k0 = 0; k0 < 512; k0 += 32) {
#pragma unroll
    for (int hh = 0; hh < 2; ++hh) {
      int r = lr + hh * 32;
      int gm = m0 + r;
      float4 av = make_float4(0.f, 0.f, 0.f, 0.f);
      if (gm < M) av = *(const float4*)(A + (size_t)gm * 512 + k0 + lc);
      *(float4*)&As[r][lc] = av;
      float4 wv = *(const float4*)(W + (size_t)(n0 + r) * 512 + k0 + lc);
      Wt[lc + 0][r] = wv.x;
      Wt[lc + 1][r] = wv.y;
      Wt[lc + 2][r] = wv.z;
      Wt[lc + 3][r] = wv.w;
    }
    __syncthreads();
#pragma unroll
    for (int kk = 0; kk < 32; kk += 4) {
      f4u a[4], w[4];
#pragma unroll
      for (int i = 0; i < 4; ++i) a[i].v = *(float4*)&As[ty * 4 + i][kk];
#pragma unroll
      for (int q = 0; q < 4; ++q) w[q].v = *(float4*)&Wt[kk + q][tx * 4];
#pragma unroll
      for (int i = 0; i < 4; ++i)
#pragma unroll
        for (int q = 0; q < 4; ++q)
#pragma unroll
          for (int j = 0; j < 4; ++j)
            acc[i][j] = fmaf(a[i].f[q], w[q].f[j], acc[i][j]);
    }
    __syncthreads();
  }

#pragma unroll
  for (int i = 0; i < 4; ++i) {
    int m = m0 + ty * 4 + i;
    if (MODE == 2 && m >= M) continue;
    int n = n0 + tx * 4;
    if constexpr (MODE == 3) {
      f4u r;
#pragma unroll
      for (int j = 0; j < 4; ++j) r.f[j] = acc[i][j] + bias[n + j];
      *(float4*)(fo + (size_t)m * 512 + n) = r.v;
    } else if constexpr (MODE == 2) {
      int hI = n >> 6, dk = n & 63;
      size_t idx = ((size_t)(hI * P_LEN + m) << 6) + dk;
      ushort4 hv, lv;
      unsigned short h;
      h = f2bf(acc[i][0]); hv.x = h; lv.x = f2bf(acc[i][0] - bf2f(h));
      h = f2bf(acc[i][1]); hv.y = h; lv.y = f2bf(acc[i][1] - bf2f(h));
      h = f2bf(acc[i][2]); hv.z = h; lv.z = f2bf(acc[i][2] - bf2f(h));
      h = f2bf(acc[i][3]); hv.w = h; lv.w = f2bf(acc[i][3] - bf2f(h));
      *(ushort4*)(o1h + idx) = hv;
      *(ushort4*)(o1l + idx) = lv;
    } else {
      int bI = m >> 10, s = m & 1023, hI = n >> 6, dk = n & 63;
      size_t idx = ((size_t)(((bI * 8 + hI) << 10) + s) << 6) + dk;
      float vb[4];
#pragma unroll
      for (int j = 0; j < 4; ++j) vb[j] = acc[i][j] + bias[n + j];
      if constexpr (MODE == 0) {
        ushort4 hv, lv;
        unsigned short h;
        h = f2bf(vb[0]); hv.x = h; lv.x = f2bf(vb[0] - bf2f(h));
        h = f2bf(vb[1]); hv.y = h; lv.y = f2bf(vb[1] - bf2f(h));
        h = f2bf(vb[2]); hv.z = h; lv.z = f2bf(vb[2] - bf2f(h));
        h = f2bf(vb[3]); hv.w = h; lv.w = f2bf(vb[3] - bf2f(h));
        *(ushort4*)(o1h + idx) = hv;
        *(ushort4*)(o1l + idx) = lv;
      } else {  // MODE 1
        ushort4 hu, lu, hv2, lv2;
        unsigned short h;
        float t;
        t = vb[0] + pbu[n + 0]; h = f2bf(t); hu.x = h; lu.x = f2bf(t - bf2f(h));
        t = vb[1] + pbu[n + 1]; h = f2bf(t); hu.y = h; lu.y = f2bf(t - bf2f(h));
        t = vb[2] + pbu[n + 2]; h = f2bf(t); hu.z = h; lu.z = f2bf(t - bf2f(h));
        t = vb[3] + pbu[n + 3]; h = f2bf(t); hu.w = h; lu.w = f2bf(t - bf2f(h));
        t = vb[0] + pbv[n + 0]; h = f2bf(t); hv2.x = h; lv2.x = f2bf(t - bf2f(h));
        t = vb[1] + pbv[n + 1]; h = f2bf(t); hv2.y = h; lv2.y = f2bf(t - bf2f(h));
        t = vb[2] + pbv[n + 2]; h = f2bf(t); hv2.z = h; lv2.z = f2bf(t - bf2f(h));
        t = vb[3] + pbv[n + 3]; h = f2bf(t); hv2.w = h; lv2.w = f2bf(t - bf2f(h));
        *(ushort4*)(o1h + idx) = hu;  *(ushort4*)(o1l + idx) = lu;
        *(ushort4*)(o2h + idx) = hv2; *(ushort4*)(o2l + idx) = lv2;
      }
    }
  }
}

// ---------------- V transpose: (BH,S,64) -> (BH,64,S), both planes --------
__global__ __launch_bounds__(256) void vtrans(
    const unsigned short* __restrict__ src_h, const unsigned short* __restrict__ src_l,
    unsigned short* __restrict__ dst_h, unsigned short* __restrict__ dst_l)
{
  __shared__ unsigned short tile[64 * 72];
  const int tid = threadIdx.x;
  const int bh = blockIdx.x >> 4, st = blockIdx.x & 15;
  const int s0 = st << 6;
  const int r = tid >> 2;
  const int c0 = (tid & 3) << 4;
  const size_t ibase = (((size_t)(bh << 10) + s0 + r) << 6) + c0;
  const size_t obase = ((size_t)(bh << 6)) << 10;
#pragma unroll
  for (int pl = 0; pl < 2; ++pl) {
    const unsigned short* src = pl ? src_l : src_h;
    unsigned short* dst = pl ? dst_l : dst_h;
    *(uint4*)&tile[r * 72 + c0] = *(const uint4*)(src + ibase);
    *(uint4*)&tile[r * 72 + c0 + 8] = *(const uint4*)(src + ibase + 8);
    __syncthreads();
    unsigned short buf[16] __attribute__((aligned(16)));
#pragma unroll
    for (int i = 0; i < 16; ++i) buf[i] = tile[(c0 + i) * 72 + r];
    *(uint4*)(dst + obase + ((size_t)r << 10) + s0 + c0) = *(uint4*)&buf[0];
    *(uint4*)(dst + obase + ((size_t)r << 10) + s0 + c0 + 8) = *(uint4*)&buf[8];
    __syncthreads();
  }
}

// ---------------- fused rel-pos flash attention (bf16-split MFMA) ---------
// 2048 blocks (XCD decode), 256 thr = 4 waves. Register-prefetch pipeline:
// K+band fragments for tile t+32 issued at top of tile t (regs survive
// barriers: compiler only waits vmcnt at first MFMA use). V frags for the
// CURRENT tile issued at top, consumed after softmax (2 barriers of cover).
#define MFMA_B(a, b, c) __builtin_amdgcn_mfma_f32_16x16x32_bf16(a, b, c, 0, 0, 0)

#define DECL_KB(S) \
  bf16x8 S##kh0, S##kh1, S##kl0, S##kl1; \
  bfz S##b0h0, S##b0h1, S##b0l0, S##b0l1, S##b1h0, S##b1h1, S##b1l0, S##b1l1;

#define LOAD_KB(S, T0V) { \
  const size_t ko_ = kbase + (((size_t)((T0V) + T0 + ln)) << 6) + (g << 3); \
  S##kh0 = *(const bf16x8*)(khh + ko_); \
  S##kh1 = *(const bf16x8*)(khh + ko_ + 32); \
  S##kl0 = *(const bf16x8*)(khl + ko_); \
  S##kl1 = *(const bf16x8*)(khl + ko_ + 32); \
  const int pm_ = 993 + (T0V) - s0 + (ct << 5) + ln; \
  if (pm_ < P_LEN) { \
    const size_t po_ = ppb + (((size_t)pm_) << 6) + (g << 3); \
    S##b0h0.v = *(const bf16x8*)(pph + po_); \
    S##b0h1.v = *(const bf16x8*)(pph + po_ + 32); \
    S##b0l0.v = *(const bf16x8*)(ppl + po_); \
    S##b0l1.v = *(const bf16x8*)(ppl + po_ + 32); \
  } else { \
    S##b0h0.u = make_uint4(0,0,0,0); S##b0h1.u = make_uint4(0,0,0,0); \
    S##b0l0.u = make_uint4(0,0,0,0); S##b0l1.u = make_uint4(0,0,0,0); } \
  if (pm_ + 16 < P_LEN) { \
    const size_t po_ = ppb + (((size_t)(pm_ + 16)) << 6) + (g << 3); \
    S##b1h0.v = *(const bf16x8*)(pph + po_); \
    S##b1h1.v = *(const bf16x8*)(pph + po_ + 32); \
    S##b1l0.v = *(const bf16x8*)(ppl + po_); \
    S##b1l1.v = *(const bf16x8*)(ppl + po_ + 32); \
  } else { \
    S##b1h0.u = make_uint4(0,0,0,0); S##b1h1.u = make_uint4(0,0,0,0); \
    S##b1l0.u = make_uint4(0,0,0,0); S##b1l1.u = make_uint4(0,0,0,0); } \
}

#define ATTN_ITER(C, N, T0C, LASTF) { \
  bf16x8 vh0_, vl0_, vh1_, vl1_; \
  { const size_t vo0_ = vtb + (((size_t)((ct << 5) + ln)) << 10) + (T0C) + (g << 3); \
    vh0_ = *(const bf16x8*)(vth + vo0_); \
    vl0_ = *(const bf16x8*)(vtl + vo0_); \
    const size_t vo1_ = vtb + (((size_t)((ct << 5) + 16 + ln)) << 10) + (T0C) + (g << 3); \
    vh1_ = *(const bf16x8*)(vth + vo1_); \
    vl1_ = *(const bf16x8*)(vtl + vo1_); } \
  if (!(LASTF)) { LOAD_KB(N, (T0C) + KT) } \
  f32x4 ac_ = {0.f, 0.f, 0.f, 0.f}; \
  ac_ = MFMA_B(qa_l[0], C##kh0, ac_); \
  ac_ = MFMA_B(qa_h[0], C##kl0, ac_); \
  ac_ = MFMA_B(qa_h[0], C##kh0, ac_); \
  ac_ = MFMA_B(qa_l[1], C##kh1, ac_); \
  ac_ = MFMA_B(qa_h[1], C##kl1, ac_); \
  ac_ = MFMA_B(qa_h[1], C##kh1, ac_); \
  f32x4 z0_ = {0.f, 0.f, 0.f, 0.f}, z1_ = {0.f, 0.f, 0.f, 0.f}; \
  z0_ = MFMA_B(qb_l[0], C##b0h0.v, z0_); \
  z0_ = MFMA_B(qb_h[0], C##b0l0.v, z0_); \
  z0_ = MFMA_B(qb_h[0], C##b0h0.v, z0_); \
  z0_ = MFMA_B(qb_l[1], C##b0h1.v, z0_); \
  z0_ = MFMA_B(qb_h[1], C##b0l1.v, z0_); \
  z0_ = MFMA_B(qb_h[1], C##b0h1.v, z0_); \
  z1_ = MFMA_B(qb_l[0], C##b1h0.v, z1_); \
  z1_ = MFMA_B(qb_h[0], C##b1l0.v, z1_); \
  z1_ = MFMA_B(qb_h[0], C##b1h0.v, z1_); \
  z1_ = MFMA_B(qb_l[1], C##b1h1.v, z1_); \
  z1_ = MFMA_B(qb_h[1], C##b1l1.v, z1_); \
  z1_ = MFMA_B(qb_h[1], C##b1h1.v, z1_); \
  { const int U0_ = (ct << 5); \
    _Pragma("unroll") for (int r = 0; r < 4; ++r) { \
      zs[(R0 + (g << 2) + r) * 68 + U0_ + ln] = z0_[r]; \
      zs[(R0 + (g << 2) + r) * 68 + U0_ + 16 + ln] = z1_[r]; } } \
  __syncthreads(); \
  { const int t_ = T0 + ln; \
    const int mval_ = mw[(b << 10) + (T0C) + t_]; \
    float sc_[4], ml_[4], sl_[4]; \
    _Pragma("unroll") for (int r = 0; r < 4; ++r) { \
      const int row_ = R0 + (g << 2) + r; \
      float bdv_ = zs[row_ * 68 + (t_ - row_ + 31)]; \
      if (wrapT && r == 0 && (T0C) == S_LEN - KT) bdv_ = wrapW; \
      float v_ = (ac_[r] + bdv_) * 0.125f; \
      sc_[r] = mval_ ? -10000.f : v_; } \
    _Pragma("unroll") for (int r = 0; r < 4; ++r) { \
      float mx_ = sc_[r]; \
      _Pragma("unroll") for (int off = 1; off < 16; off <<= 1) \
        mx_ = fmaxf(mx_, __shfl_xor(mx_, off)); \
      ml_[r] = mx_; \
      float e_ = __expf(sc_[r] - mx_); \
      float s_ = e_; \
      _Pragma("unroll") for (int off = 1; off < 16; off <<= 1) \
        s_ += __shfl_xor(s_, off); \
      sl_[r] = s_; sc_[r] = e_; } \
    if (ln == 0) { \
      _Pragma("unroll") for (int r = 0; r < 4; ++r) { \
        red[ct][R0 + (g << 2) + r][0] = ml_[r]; \
        red[ct][R0 + (g << 2) + r][1] = sl_[r]; } } \
    __syncthreads(); \
    _Pragma("unroll") for (int r = 0; r < 4; ++r) { \
      const int row_ = R0 + (g << 2) + r; \
      const float mo_ = red[ct ^ 1][row_][0]; \
      const float so_ = red[ct ^ 1][row_][1]; \
      const float mn_ = fmaxf(m_run[r], fmaxf(ml_[r], mo_)); \
      const float corr_ = __expf(m_run[r] - mn_); \
      l_run[r] = l_run[r] * corr_ + sl_[r] * __expf(ml_[r] - mn_) + so_ * __expf(mo_ - mn_); \
      m_run[r] = mn_; \
      oA0[r] *= corr_; oA1[r] *= corr_; \
      const float p_ = sc_[r] * __expf(ml_[r] - mn_); \
      const unsigned short hp_ = f2bf(p_); \
      ph_s[row_ * 40 + t_] = hp_; \
      pl_s[row_ * 40 + t_] = f2bf(p_ - bf2f(hp_)); } \
    __syncthreads(); } \
  { bf16x8 pa_h_ = *(const bf16x8*)&ph_s[(R0 + ln) * 40 + (g << 3)]; \
    bf16x8 pa_l_ = *(const bf16x8*)&pl_s[(R0 + ln) * 40 + (g << 3)]; \
    oA0 = MFMA_B(pa_l_, vh0_, oA0); \
    oA0 = MFMA_B(pa_h_, vl0_, oA0); \
    oA0 = MFMA_B(pa_h_, vh0_, oA0); \
    oA1 = MFMA_B(pa_l_, vh1_, oA1); \
    oA1 = MFMA_B(pa_h_, vl1_, oA1); \
    oA1 = MFMA_B(pa_h_, vh1_, oA1); } \
}

__global__ __launch_bounds__(256, 2) void attn_kernel(
    const unsigned short* __restrict__ quh, const unsigned short* __restrict__ qul,
    const unsigned short* __restrict__ qvh, const unsigned short* __restrict__ qvl,
    const unsigned short* __restrict__ khh, const unsigned short* __restrict__ khl,
    const unsigned short* __restrict__ vth, const unsigned short* __restrict__ vtl,
    const unsigned short* __restrict__ pph, const unsigned short* __restrict__ ppl,
    const int* __restrict__ mw, float* __restrict__ ctx)
{
  __shared__ float zs[32 * 68];
  __shared__ unsigned short ph_s[32 * 40], pl_s[32 * 40];
  __shared__ float red[2][32][2];

  const int tid = threadIdx.x;
  const int wid = tid >> 6, lane = tid & 63;
  const int g = lane >> 4, ln = lane & 15;
  const int rt = wid >> 1, ct = wid & 1;
  const int R0 = rt << 4, T0 = ct << 4;

  const int bid = blockIdx.x;
  const int xcd = bid & 7;
  const int i0 = bid >> 3;
  const int bh = (xcd << 3) + (i0 >> 5);
  const int s0 = (i0 & 31) * QT;
  const int b = bh >> 3, h = bh & 7;

  const size_t qbase = ((size_t)((bh << 10) + s0)) << 6;
  const size_t kbase = ((size_t)(bh << 10)) << 6;
  const size_t vtb = ((size_t)(bh << 6)) << 10;
  const size_t ppb = ((size_t)(h * P_LEN)) << 6;

  // ---- preload Q fragments (block-resident)
  bf16x8 qa_h[2], qa_l[2], qb_h[2], qb_l[2];
  {
    const size_t qo = qbase + (((size_t)(R0 + ln)) << 6) + (g << 3);
#pragma unroll
    for (int dblk = 0; dblk < 2; ++dblk) {
      qa_h[dblk] = *(const bf16x8*)(quh + qo + dblk * 32);
      qa_l[dblk] = *(const bf16x8*)(qul + qo + dblk * 32);
      qb_h[dblk] = *(const bf16x8*)(qvh + qo + dblk * 32);
      qb_l[dblk] = *(const bf16x8*)(qvl + qo + dblk * 32);
    }
  }

  // ---- rel_shift wrap element z[0,1023] = qv[1] . pp[0]
  float wrapW = 0.f;
  if (s0 == 0) {
    const unsigned short* q1h = qvh + ((((size_t)(bh << 10)) + 1) << 6);
    const unsigned short* q1l = qvl + ((((size_t)(bh << 10)) + 1) << 6);
    for (int d = 0; d < 64; ++d)
      wrapW += (bf2f(q1h[d]) + bf2f(q1l[d])) * (bf2f(pph[ppb + d]) + bf2f(ppl[ppb + d]));
  }
  const bool wrapT = (s0 == 0) && (wid == 1) && (lane == 15);

  f32x4 oA0 = {0.f, 0.f, 0.f, 0.f}, oA1 = {0.f, 0.f, 0.f, 0.f};
  float m_run[4], l_run[4];
#pragma unroll
  for (int r = 0; r < 4; ++r) { m_run[r] = -1e30f; l_run[r] = 0.f; }

  DECL_KB(A_) DECL_KB(B_)
  LOAD_KB(A_, 0)

  for (int t0 = 0; t0 < S_LEN - 64; t0 += 64) {
    ATTN_ITER(A_, B_, t0, 0)
    ATTN_ITER(B_, A_, t0 + 32, 0)
  }
  ATTN_ITER(A_, B_, S_LEN - 64, 0)
  ATTN_ITER(B_, A_, S_LEN - 32, 1)

  // ---- epilogue
#pragma unroll
  for (int r = 0; r < 4; ++r) {
    const float inv = 1.0f / l_run[r];
    const int s = s0 + R0 + (g << 2) + r;
    float* cp = ctx + (((size_t)((b << 10) + s)) << 9) + (h << 6);
    cp[(ct << 5) + ln] = oA0[r] * inv;
    cp[(ct << 5) + 16 + ln] = oA1[r] * inv;
  }
}

// --------------------------------------------------------------------------
extern "C" void kernel_launch(void* const* d_in, const int* in_sizes, int n_in,
                              void* d_out, int out_size, void* d_ws, size_t ws_size,
                              hipStream_t stream) {
  const float* q    = (const float*)d_in[0];
  const float* k    = (const float*)d_in[1];
  const float* v    = (const float*)d_in[2];
  const float* pos  = (const float*)d_in[3];
  const void*  mask = d_in[4];
  const float* Wq   = (const float*)d_in[5];
  const float* bq   = (const float*)d_in[6];
  const float* Wk   = (const float*)d_in[7];
  const float* bk   = (const float*)d_in[8];
  const float* Wv   = (const float*)d_in[9];
  const float* bv   = (const float*)d_in[10];
  const float* Wo   = (const float*)d_in[11];
  const float* bo   = (const float*)d_in[12];
  const float* Wpos = (const float*)d_in[13];
  const float* pbu  = (const float*)d_in[14];
  const float* pbv  = (const float*)d_in[15];
  float* out = (float*)d_out;

  unsigned short* us = (unsigned short*)d_ws;
  const size_t SZ  = (size_t)B_SZ * N_HEAD * S_LEN * 64;   // 4,194,304
  const size_t SZP = (size_t)N_HEAD * P_LEN * 64;          // 1,048,064
  unsigned short* quh = us;
  unsigned short* qul = quh + SZ;
  unsigned short* qvh = qul + SZ;
  unsigned short* qvl = qvh + SZ;
  unsigned short* khh = qvl + SZ;
  unsigned short* khl = khh + SZ;
  unsigned short* vth = khl + SZ;
  unsigned short* vtl = vth + SZ;
  unsigned short* pph = vtl + SZ;
  unsigned short* ppl = pph + SZP;
  float* ctxW = (float*)(ppl + SZP);
  unsigned short* vhh = (unsigned short*)ctxW;   // overlay, consumed by vtrans
  unsigned short* vhl = vhh + SZ;
  int* mwW = (int*)(ctxW + SZ);

  mask_prep<<<dim3(B_SZ * S_LEN / 256), 256, 0, stream>>>(mask, mwW);

  gemm512<1><<<dim3(128, 8), 256, 0, stream>>>(q, Wq, bq, pbu, pbv, nullptr,
                                               quh, qul, qvh, qvl, 8192);
  gemm512<0><<<dim3(128, 8), 256, 0, stream>>>(k, Wk, bk, nullptr, nullptr, nullptr,
                                               khh, khl, nullptr, nullptr, 8192);
  gemm512<0><<<dim3(128, 8), 256, 0, stream>>>(v, Wv, bv, nullptr, nullptr, nullptr,
                                               vhh, vhl, nullptr, nullptr, 8192);
  gemm512<2><<<dim3(32, 8), 256, 0, stream>>>(pos, Wpos, nullptr, nullptr, nullptr, nullptr,
                                              pph, ppl, nullptr, nullptr, P_LEN);

  vtrans<<<dim3(64 * 16), 256, 0, stream>>>(vhh, vhl, vth, vtl);

  attn_kernel<<<dim3(2048), 256, 0, stream>>>(quh, qul, qvh, qvl, khh, khl,
                                              vth, vtl, pph, ppl, mwW, ctxW);

  gemm512<3><<<dim3(128, 8), 256, 0, stream>>>(ctxW, Wo, bo, nullptr, nullptr, out,
                                               nullptr, nullptr, nullptr, nullptr, 8192);
}